// Round 11
// baseline (59.608 us; speedup 1.0000x reference)
//
#include <hip/hip_runtime.h>

#define K_DIM 4096
#define N_DIM 8192
#define PREFIX 1024             // prefix columns used for the underflow test
#define PC4 (PREFIX / 4)        // 256 f32x4 per row in prefix
#define TAILC (N_DIM - PREFIX)  // 7168 tail columns
#define TC4 (TAILC / 4)         // 1792 f32x4 per row in tail
#define RB 256                  // row-blocks for both colsum kernels (16 rows each)

typedef float f32x4 __attribute__((ext_vector_type(4)));
typedef int   i32x4 __attribute__((ext_vector_type(4)));
typedef unsigned int u32x4 __attribute__((ext_vector_type(4)));

// ws float layout (all plain stores / same-launch producers, no pre-zeroing):
// partial0 [RB*PREFIX]  (1 MB)   prefix colsum partials
// partial1 [RB*TAILC]   (7 MB)   tail colsum partials (slow path only)
// prior_eps[N], dope[N], Tprod[PREFIX], colsum_new[N]
// flag(int), counter(int), worklist[K], nzp[RB]

__device__ __forceinline__ float fast_tanh_half(float h) {
    // tanh(h/2) = 1 - 2/(e^h + 1)
    float e = __expf(h);
    float r = __builtin_amdgcn_rcpf(e + 1.0f);
    return __builtin_fmaf(-2.0f, r, 1.0f);
}

// clip(2*atanh(P/t), -1, 1) for t != 0, else 0.   2*atanh(P/t) = ln((t+P)/(t-P))
__device__ __forceinline__ float check_msg(float t, float P) {
    float q = (t + P) * __builtin_amdgcn_rcpf(t - P);
    float m = 0.69314718055994531f * __log2f(q);
    m = fminf(fmaxf(m, -1.0f), 1.0f);
    return (t == 0.0f) ? 0.0f : m;
}

// D1: column sums of Hxs[:, 0:PREFIX]. grid=RB x 256. Block b: rows [16b,16b+16).
__global__ __launch_bounds__(256) void prefix_colsum_kernel(const float* __restrict__ Hxs,
                                                            float* __restrict__ partial0,
                                                            int* __restrict__ nzp) {
    const int t = threadIdx.x;
    const int b = blockIdx.x;
    const f32x4* p = reinterpret_cast<const f32x4*>(Hxs + (size_t)b * 16 * N_DIM);
    f32x4 acc = {0.f, 0.f, 0.f, 0.f};
    unsigned int nzbits = 0u;
    #pragma unroll
    for (int r = 0; r < 16; ++r) {
        f32x4 v = __builtin_nontemporal_load(&p[(size_t)r * (N_DIM / 4) + t]);
        acc.x += v.x; acc.y += v.y; acc.z += v.z; acc.w += v.w;
        u32x4 u;
        __builtin_memcpy(&u, &v, 16);
        nzbits |= (u.x | u.y | u.z | u.w);
    }
    reinterpret_cast<f32x4*>(partial0 + (size_t)b * PREFIX)[t] = acc;

    __shared__ int snz;
    if (t == 0) snz = 0;
    __syncthreads();
    if (__any(nzbits != 0u ? 1 : 0)) {
        if ((t & 63) == 0) atomicOr(&snz, 1);
    }
    __syncthreads();
    if (t == 0) nzp[b] = snz;
}

// D2: prep. grid = 32 x 256 (one thread per column n).
// dope[n] all N; colsum_new[n]=0; n<PREFIX: reduce partials -> prior_eps, Tprod.
// Block 0: flag from nzp; counter=0.
__global__ __launch_bounds__(256) void prep_kernel(const float* __restrict__ ps,
                                                   const float* __restrict__ Min,
                                                   const float* __restrict__ partial0,
                                                   const int* __restrict__ nzp,
                                                   float* __restrict__ prior_eps,
                                                   float* __restrict__ dope_out,
                                                   float* __restrict__ Tprod,
                                                   float* __restrict__ colsum_new,
                                                   int* __restrict__ flag,
                                                   int* __restrict__ counter) {
    const int t = threadIdx.x;
    const int n = blockIdx.x * 256 + t;

    float p0 = ps[2 * n], p1 = ps[2 * n + 1];
    float p1n = p1 / (p0 + p1);
    float dope = logf(1.0f - p1n) - logf(p1n);
    dope_out[n] = dope;
    colsum_new[n] = 0.0f;

    if (blockIdx.x == 0) {
        __shared__ int w[4];
        int v = nzp[t];
        int any = __any(v != 0 ? 1 : 0) ? 1 : 0;
        if ((t & 63) == 0) w[t >> 6] = any;
        __syncthreads();
        if (t == 0) {
            flag[0] = (w[0] | w[1] | w[2] | w[3]);
            counter[0] = 0;
        }
    }

    if (n < PREFIX) {
        float cs = 0.0f;
        #pragma unroll 8
        for (int i = 0; i < RB; ++i)
            cs += partial0[(size_t)i * PREFIX + n];

        float m0 = Min[2 * n], m1 = Min[2 * n + 1];
        float m1n = m1 / (m0 + m1);
        float phi = logf(1.0f - m1n) - logf(m1n);

        float prior = dope + phi + cs;
        prior = fminf(fmaxf(prior, -100.0f), 100.0f);
        float pe = prior + 1e-4f;
        prior_eps[n] = pe;
        float T = tanhf(pe * 0.5f);
        Tprod[n] = (T == 0.0f) ? 1.0f : T;
    }
}

// D3: main. ONE WAVE = ONE ROW, no barriers. grid = K/4 x 256.
// Prefix product over cols 0:PREFIX; |t|<=1 => monotone, so prefix==0 => full
// product == 0 => all outputs of the row are exactly 0 -> nt zero-stream.
// Else: append row to worklist (fixup writes it later).
__global__ __launch_bounds__(256) void main_kernel(const float* __restrict__ Hxs,
                                                   const int* __restrict__ H,
                                                   const float* __restrict__ prior_eps,
                                                   const float* __restrict__ Tprod,
                                                   const int* __restrict__ flag,
                                                   float* __restrict__ out,
                                                   int* __restrict__ counter,
                                                   int* __restrict__ worklist) {
    const int lane = threadIdx.x & 63;
    const int k = blockIdx.x * 4 + (threadIdx.x >> 6);

    const bool fast = (*flag == 0);
    const i32x4* H4  = reinterpret_cast<const i32x4*>(H + (size_t)k * N_DIM);
    const f32x4* TP4 = reinterpret_cast<const f32x4*>(Tprod);
    const f32x4* PE4 = reinterpret_cast<const f32x4*>(prior_eps);
    const f32x4* HX4 = reinterpret_cast<const f32x4*>(Hxs + (size_t)k * N_DIM);

    float lp0 = 1.f, lp1 = 1.f, lp2 = 1.f, lp3 = 1.f;
    #pragma unroll
    for (int u = 0; u < 4; ++u) {
        const int idx = u * 64 + lane;       // int4 idx 0..255 = cols 0..1023
        const i32x4 hh = H4[idx];
        float f;
        if (fast) {
            const f32x4 tv = TP4[idx];
            float f0 = hh.x ? tv.x : 1.f;
            float f1 = hh.y ? tv.y : 1.f;
            float f2 = hh.z ? tv.z : 1.f;
            float f3 = hh.w ? tv.w : 1.f;
            f = (f0 * f1) * (f2 * f3);
        } else {
            const f32x4 pe = PE4[idx];
            const f32x4 hx = HX4[idx];
            float t0 = fast_tanh_half((hh.x ? pe.x : 0.f) - hx.x);
            float t1 = fast_tanh_half((hh.y ? pe.y : 0.f) - hx.y);
            float t2 = fast_tanh_half((hh.z ? pe.z : 0.f) - hx.z);
            float t3 = fast_tanh_half((hh.w ? pe.w : 0.f) - hx.w);
            t0 = (t0 == 0.f) ? 1.f : t0;
            t1 = (t1 == 0.f) ? 1.f : t1;
            t2 = (t2 == 0.f) ? 1.f : t2;
            t3 = (t3 == 0.f) ? 1.f : t3;
            f = (t0 * t1) * (t2 * t3);
        }
        if (u == 0) lp0 *= f;
        if (u == 1) lp1 *= f;
        if (u == 2) lp2 *= f;
        if (u == 3) lp3 *= f;
    }
    float pp = (lp0 * lp1) * (lp2 * lp3);
    #pragma unroll
    for (int off = 1; off < 64; off <<= 1)
        pp *= __shfl_xor(pp, off);

    if (pp == 0.0f) {
        f32x4* orow = reinterpret_cast<f32x4*>(out + (size_t)k * N_DIM);
        const f32x4 z = {0.f, 0.f, 0.f, 0.f};
        #pragma unroll
        for (int s = 0; s < 32; ++s)
            __builtin_nontemporal_store(z, &orow[s * 64 + lane]);
    } else {
        if (lane == 0) {
            int i = atomicAdd(counter, 1);
            worklist[i] = k;
        }
    }
}

// D4: tail colsum (cols PREFIX:N) -- runs only if worklist non-empty.
// grid = RB x 256. Block b: rows [16b,16b+16), 7 f32x4 per thread per row.
__global__ __launch_bounds__(256) void tail_colsum_kernel(const float* __restrict__ Hxs,
                                                          const int* __restrict__ counter,
                                                          float* __restrict__ partial1) {
    if (*counter == 0) return;
    const int t = threadIdx.x;
    const int b = blockIdx.x;
    const f32x4* p = reinterpret_cast<const f32x4*>(Hxs + (size_t)b * 16 * N_DIM + PREFIX);
    f32x4 acc[7];
    #pragma unroll
    for (int c = 0; c < 7; ++c) acc[c] = (f32x4){0.f, 0.f, 0.f, 0.f};
    for (int r = 0; r < 16; ++r) {
        #pragma unroll
        for (int c = 0; c < 7; ++c) {
            f32x4 v = p[(size_t)r * (N_DIM / 4) + c * 256 + t];
            acc[c].x += v.x; acc[c].y += v.y; acc[c].z += v.z; acc[c].w += v.w;
        }
    }
    f32x4* pr = reinterpret_cast<f32x4*>(partial1 + (size_t)b * TAILC);
    #pragma unroll
    for (int c = 0; c < 7; ++c) pr[c * 256 + t] = acc[c];
}

// D5: tail prep -> prior_eps for cols PREFIX:N. grid = 28 x 256.
__global__ __launch_bounds__(256) void prep_tail_kernel(const float* __restrict__ Min,
                                                        const float* __restrict__ dope,
                                                        const float* __restrict__ partial1,
                                                        const int* __restrict__ counter,
                                                        float* __restrict__ prior_eps) {
    if (*counter == 0) return;
    const int j = blockIdx.x * 256 + threadIdx.x;   // 0..TAILC-1
    const int n = PREFIX + j;
    float cs = 0.0f;
    #pragma unroll 8
    for (int i = 0; i < RB; ++i)
        cs += partial1[(size_t)i * TAILC + j];

    float m0 = Min[2 * n], m1 = Min[2 * n + 1];
    float m1n = m1 / (m0 + m1);
    float phi = logf(1.0f - m1n) - logf(m1n);

    float prior = dope[n] + phi + cs;
    prior = fminf(fmaxf(prior, -100.0f), 100.0f);
    prior_eps[n] = prior + 1e-4f;
}

// D6: fixup -- full general-path recompute for worklist rows. grid = 64 x 256.
__global__ __launch_bounds__(256) void fixup_kernel(const float* __restrict__ Hxs,
                                                    const int* __restrict__ H,
                                                    const int* __restrict__ x,
                                                    const float* __restrict__ prior_eps,
                                                    const int* __restrict__ counter,
                                                    const int* __restrict__ worklist,
                                                    float* __restrict__ out,
                                                    float* __restrict__ colsum_new) {
    const int count = *counter;
    if (count == 0) return;
    const int lane = threadIdx.x & 63;
    const int wave = blockIdx.x * 4 + (threadIdx.x >> 6);

    for (int i = wave; i < count; i += 256) {
        const int k = worklist[i];
        const i32x4* H4  = reinterpret_cast<const i32x4*>(H + (size_t)k * N_DIM);
        const f32x4* PE4 = reinterpret_cast<const f32x4*>(prior_eps);
        const f32x4* HX4 = reinterpret_cast<const f32x4*>(Hxs + (size_t)k * N_DIM);

        float lp = 1.0f;
        for (int s = 0; s < 32; ++s) {
            const int idx = s * 64 + lane;
            const i32x4 hh = H4[idx];
            const f32x4 pe = PE4[idx];
            const f32x4 hx = HX4[idx];
            float t0 = fast_tanh_half((hh.x ? pe.x : 0.f) - hx.x);
            float t1 = fast_tanh_half((hh.y ? pe.y : 0.f) - hx.y);
            float t2 = fast_tanh_half((hh.z ? pe.z : 0.f) - hx.z);
            float t3 = fast_tanh_half((hh.w ? pe.w : 0.f) - hx.w);
            t0 = (t0 == 0.f) ? 1.f : t0;
            t1 = (t1 == 0.f) ? 1.f : t1;
            t2 = (t2 == 0.f) ? 1.f : t2;
            t3 = (t3 == 0.f) ? 1.f : t3;
            lp *= (t0 * t1) * (t2 * t3);
        }
        #pragma unroll
        for (int off = 1; off < 64; off <<= 1)
            lp *= __shfl_xor(lp, off);

        const float sgn = 1.0f - 2.0f * (float)x[k];
        const float P = sgn * lp;

        f32x4* orow = reinterpret_cast<f32x4*>(out + (size_t)k * N_DIM);
        for (int s = 0; s < 32; ++s) {
            const int idx = s * 64 + lane;
            const i32x4 hh = H4[idx];
            const f32x4 pe = PE4[idx];
            const f32x4 hx = HX4[idx];
            float t0 = fast_tanh_half((hh.x ? pe.x : 0.f) - hx.x);
            float t1 = fast_tanh_half((hh.y ? pe.y : 0.f) - hx.y);
            float t2 = fast_tanh_half((hh.z ? pe.z : 0.f) - hx.z);
            float t3 = fast_tanh_half((hh.w ? pe.w : 0.f) - hx.w);
            f32x4 o;
            o.x = check_msg(t0, P);
            o.y = check_msg(t1, P);
            o.z = check_msg(t2, P);
            o.w = check_msg(t3, P);
            orow[idx] = o;
            const int n0 = idx * 4;
            if (o.x != 0.f) atomicAdd(&colsum_new[n0 + 0], o.x);
            if (o.y != 0.f) atomicAdd(&colsum_new[n0 + 1], o.y);
            if (o.z != 0.f) atomicAdd(&colsum_new[n0 + 2], o.z);
            if (o.w != 0.f) atomicAdd(&colsum_new[n0 + 3], o.w);
        }
    }
}

// D7: output beliefs. grid = 32 x 256.
__global__ __launch_bounds__(256) void final_kernel(const float* __restrict__ colsum_new,
                                                    const float* __restrict__ dope,
                                                    float* __restrict__ Mout) {
    const int n = blockIdx.x * 256 + threadIdx.x;
    float z = (1.0f - tanhf((colsum_new[n] + dope[n]) * 0.5f)) * 0.5f;
    float2 m; m.x = 1.0f - z; m.y = z;
    reinterpret_cast<float2*>(Mout)[n] = m;
}

extern "C" void kernel_launch(void* const* d_in, const int* in_sizes, int n_in,
                              void* d_out, int out_size, void* d_ws, size_t ws_size,
                              hipStream_t stream) {
    (void)in_sizes; (void)n_in; (void)out_size; (void)ws_size;
    const float* ps  = (const float*)d_in[0];
    const float* Min = (const float*)d_in[1];
    const float* Hxs = (const float*)d_in[2];
    const int*   x   = (const int*)d_in[3];
    const int*   H   = (const int*)d_in[4];

    float* out = (float*)d_out;
    float* Mout = out;                       // N*2 floats
    float* Hxs_new = out + 2 * N_DIM;        // K*N floats

    float* ws = (float*)d_ws;
    float* partial0   = ws;                                   // RB*PREFIX (1 MB)
    float* partial1   = partial0 + (size_t)RB * PREFIX;       // RB*TAILC (7 MB)
    float* prior_eps  = partial1 + (size_t)RB * TAILC;        // N
    float* dope       = prior_eps + N_DIM;                    // N
    float* Tprod      = dope + N_DIM;                         // PREFIX
    float* colsum_new = Tprod + PREFIX;                       // N
    int*   flag       = (int*)(colsum_new + N_DIM);
    int*   counter    = flag + 64;
    int*   worklist   = counter + 64;                         // K ints
    int*   nzp        = worklist + K_DIM;                     // RB ints

    prefix_colsum_kernel<<<RB, 256, 0, stream>>>(Hxs, partial0, nzp);

    prep_kernel<<<N_DIM / 256, 256, 0, stream>>>(ps, Min, partial0, nzp,
                                                 prior_eps, dope, Tprod,
                                                 colsum_new, flag, counter);

    main_kernel<<<K_DIM / 4, 256, 0, stream>>>(Hxs, H, prior_eps, Tprod, flag,
                                               Hxs_new, counter, worklist);

    tail_colsum_kernel<<<RB, 256, 0, stream>>>(Hxs, counter, partial1);

    prep_tail_kernel<<<TAILC / 256, 256, 0, stream>>>(Min, dope, partial1,
                                                      counter, prior_eps);

    fixup_kernel<<<64, 256, 0, stream>>>(Hxs, H, x, prior_eps, counter,
                                         worklist, Hxs_new, colsum_new);

    final_kernel<<<N_DIM / 256, 256, 0, stream>>>(colsum_new, dope, Mout);
}